// Round 3
// baseline (144.912 us; speedup 1.0000x reference)
//
#include <hip/hip_runtime.h>

#define POOL_H 7
#define POOL_W 7
#define CHANS  256

// ---------------------------------------------------------------------------
// Kernel 1: per-ROI pyramid level + STABLE counting sort by level (matches
// jnp.argsort(lvl, stable=True)) for the OUTPUT order, plus a second,
// spatial-bucket counting sort that defines the EXECUTION order of kernel 2.
// Output order is fixed by the reference; execution order is any bijection.
// Bucket key = (lvl, y1/128, x1/128): blocks with overlapping feature windows
// become temporally adjacent -> cross-ROI dup loads hit L2 instead of HBM.
// ---------------------------------------------------------------------------
__global__ void __launch_bounds__(1024) level_sort_kernel(
    const float* __restrict__ rois, int N,
    int* __restrict__ sorted_lvl, float4* __restrict__ sorted_box,
    int* __restrict__ exec_slot)
{
    __shared__ int hist[16][4];   // [wave][level] for the stable output sort
    __shared__ int bin[256];      // spatial-bucket counts
    __shared__ int binbase[256];  // exclusive prefix
    __shared__ int bincnt[256];   // arrival counters

    const int tid  = threadIdx.x;
    const int wave = tid >> 6;
    const int lane = tid & 63;

    int lvl = -1, key2 = 0;
    float y1 = 0.f, x1 = 0.f, y2 = 0.f, x2 = 0.f;
    if (tid < N) {
        y1 = rois[tid * 4 + 0];
        x1 = rois[tid * 4 + 1];
        y2 = rois[tid * 4 + 2];
        x2 = rois[tid * 4 + 3];
        float h = y2 - y1;
        float w = x2 - x1;
        // lvl = round(log(sqrt(h*w))/log(2) - 5), clip [0,3]; rintf = RNE.
        // Precise logf kept: v_log_f32 could flip a ROI at a level boundary.
        float l = logf(sqrtf(h * w)) / logf(2.0f);
        int li = (int)rintf(l - 5.0f);
        lvl = li < 0 ? 0 : (li > 3 ? 3 : li);
        int yb = (int)(y1 * (1.0f / 128.0f)); yb = yb < 0 ? 0 : (yb > 7 ? 7 : yb);
        int xb = (int)(x1 * (1.0f / 128.0f)); xb = xb < 0 ? 0 : (xb > 7 ? 7 : xb);
        key2 = lvl * 64 + yb * 8 + xb;
    }

    unsigned long long mask[4];
    #pragma unroll
    for (int l = 0; l < 4; ++l) mask[l] = __ballot(lvl == l);
    if (lane == 0) {
        #pragma unroll
        for (int l = 0; l < 4; ++l) hist[wave][l] = __popcll(mask[l]);
    }
    if (tid < 256) { bin[tid] = 0; bincnt[tid] = 0; }
    __syncthreads();

    int pos = -1;
    if (lvl >= 0) {
        pos = __popcll(mask[lvl] & ((1ull << lane) - 1ull));
        for (int w2 = 0; w2 < wave; ++w2) pos += hist[w2][lvl];
        for (int l = 0; l < lvl; ++l)
            #pragma unroll
            for (int w2 = 0; w2 < 16; ++w2) pos += hist[w2][l];

        sorted_lvl[pos] = lvl;
        const float inv = 1.0f / 1024.0f;   // exact (power of two)
        sorted_box[pos] = make_float4(y1 * inv, x1 * inv, y2 * inv, x2 * inv);
        atomicAdd(&bin[key2], 1);
    }
    __syncthreads();

    if (tid == 0) {
        int acc = 0;
        for (int k = 0; k < 256; ++k) { binbase[k] = acc; acc += bin[k]; }
    }
    __syncthreads();

    if (lvl >= 0) {
        int e = binbase[key2] + atomicAdd(&bincnt[key2], 1);
        exec_slot[e] = pos;   // execution position e -> output slot pos
    }
}

// ---------------------------------------------------------------------------
// Kernel 2: ONE BLOCK PER ROI. 448 threads = 7 waves; wave = pool row py,
// px loop unrolled. Intra-ROI reuse: each wave's two feature rows (~24 KB)
// live in L1 across the 7 px; adjacent waves share a row via L2.
// Cross-ROI reuse: block b executes output slot exec_slot[(b%8)*(N/8)+b/8] --
// XCD-chunked spatial order, so each XCD walks a contiguous spatial run of
// ROIs and overlapping windows hit its own L2.
// Lane l handles channels [4l,4l+4) as float4: 16B/lane coalesced.
// ---------------------------------------------------------------------------
__global__ void __launch_bounds__(448) roi_align_kernel(
    const float* __restrict__ f0, const float* __restrict__ f1,
    const float* __restrict__ f2, const float* __restrict__ f3,
    const int* __restrict__ sorted_lvl, const float4* __restrict__ sorted_box,
    const int* __restrict__ exec_slot, int N,
    float* __restrict__ out)
{
    const int b    = blockIdx.x;
    const int py   = threadIdx.x >> 6;   // 0..6  (wave index = pool row)
    const int lane = threadIdx.x & 63;   // channel group

    // XCD-aware chunking: consecutive exec positions land on the same XCD.
    const int p = (N % 8 == 0) ? ((b & 7) * (N >> 3) + (b >> 3)) : b;
    const int slot = exec_slot[p];

    const int lvl = sorted_lvl[slot];
    const float4 box = sorted_box[slot];

    const float* feat;
    int HW;
    switch (lvl) {
        case 0:  feat = f0; HW = 256; break;
        case 1:  feat = f1; HW = 128; break;
        case 2:  feat = f2; HW = 64;  break;
        default: feat = f3; HW = 32;  break;
    }
    const float Hm1 = (float)(HW - 1);

    // iy = y1*(H-1) + py * (y2-y1)*(H-1)/6   (same for x, W=H)
    const float sy = (box.z - box.x) * Hm1 * (1.0f / 6.0f);
    const float sx = (box.w - box.y) * Hm1 * (1.0f / 6.0f);

    const float iy  = box.x * Hm1 + (float)py * sy;
    const float y0f = floorf(iy);
    const float ly  = iy - y0f;
    int y0  = (int)y0f;
    int y1i = y0 + 1;
    y0  = min(max(y0,  0), HW - 1);
    y1i = min(max(y1i, 0), HW - 1);
    const bool vy = (iy >= 0.0f) & (iy <= Hm1);

    // Per-wave row bases: all px iterations read from these two feature rows.
    const float4* row0 = (const float4*)(feat + (size_t)(y0  * HW) * CHANS) + lane;
    const float4* row1 = (const float4*)(feat + (size_t)(y1i * HW) * CHANS) + lane;

    float4* outp = (float4*)(out + (size_t)slot * (POOL_H * POOL_W * CHANS))
                   + py * (POOL_W * 64) + lane;

    const float ix_base = box.y * Hm1;

    #pragma unroll
    for (int px = 0; px < POOL_W; ++px) {
        const float ix  = ix_base + (float)px * sx;
        const float x0f = floorf(ix);
        const float lx  = ix - x0f;
        int x0  = (int)x0f;
        int x1i = x0 + 1;
        x0  = min(max(x0,  0), HW - 1);
        x1i = min(max(x1i, 0), HW - 1);
        const bool valid = vy & (ix >= 0.0f) & (ix <= Hm1);

        const float4 f00 = row0[(size_t)x0  * 64];
        const float4 f01 = row0[(size_t)x1i * 64];
        const float4 f10 = row1[(size_t)x0  * 64];
        const float4 f11 = row1[(size_t)x1i * 64];

        float4 val;
        {
            float tx, bx;
            tx = f00.x + (f01.x - f00.x) * lx;
            bx = f10.x + (f11.x - f10.x) * lx;
            val.x = tx + (bx - tx) * ly;
            tx = f00.y + (f01.y - f00.y) * lx;
            bx = f10.y + (f11.y - f10.y) * lx;
            val.y = tx + (bx - tx) * ly;
            tx = f00.z + (f01.z - f00.z) * lx;
            bx = f10.z + (f11.z - f10.z) * lx;
            val.z = tx + (bx - tx) * ly;
            tx = f00.w + (f01.w - f00.w) * lx;
            bx = f10.w + (f11.w - f10.w) * lx;
            val.w = tx + (bx - tx) * ly;
        }
        if (!valid) { val.x = 0.f; val.y = 0.f; val.z = 0.f; val.w = 0.f; }

        outp[px * 64] = val;
    }
}

extern "C" void kernel_launch(void* const* d_in, const int* in_sizes, int n_in,
                              void* d_out, int out_size, void* d_ws, size_t ws_size,
                              hipStream_t stream) {
    const float* f0   = (const float*)d_in[0];
    const float* f1   = (const float*)d_in[1];
    const float* f2   = (const float*)d_in[2];
    const float* f3   = (const float*)d_in[3];
    const float* rois = (const float*)d_in[4];
    const int N = in_sizes[4] / 4;

    int*    sorted_lvl = (int*)d_ws;
    float4* sorted_box = (float4*)((char*)d_ws + 4096);
    int*    exec_slot  = (int*)((char*)d_ws + 24576);
    float*  out        = (float*)d_out;

    hipLaunchKernelGGL(level_sort_kernel, dim3(1), dim3(1024), 0, stream,
                       rois, N, sorted_lvl, sorted_box, exec_slot);

    hipLaunchKernelGGL(roi_align_kernel, dim3(N), dim3(448), 0, stream,
                       f0, f1, f2, f3, sorted_lvl, sorted_box, exec_slot, N, out);
}

// Round 4
// 134.919 us; speedup vs baseline: 1.0741x; 1.0741x over previous
//
#include <hip/hip_runtime.h>

#define POOL_H 7
#define POOL_W 7
#define CHANS  256

// ---------------------------------------------------------------------------
// Kernel 1: per-ROI pyramid level + STABLE counting sort by level (matches
// jnp.argsort(lvl, stable=True)). Single block, 1024 threads (N=1000).
// Round-0 version: no spatial binning, no serial prefix scan (those cost
// ~4-5 us in round 3 for negative benefit).
// Keeps the precise logf path: hardware v_log_f32 risks flipping a ROI at a
// level boundary (O(1) output error); this kernel is ~3 us, not worth it.
// ---------------------------------------------------------------------------
__global__ void __launch_bounds__(1024) level_sort_kernel(
    const float* __restrict__ rois, int N,
    int* __restrict__ sorted_lvl, float4* __restrict__ sorted_box)
{
    __shared__ int hist[16][4];   // [wave][level]

    const int tid  = threadIdx.x;
    const int wave = tid >> 6;
    const int lane = tid & 63;

    int lvl = -1;
    float y1 = 0.f, x1 = 0.f, y2 = 0.f, x2 = 0.f;
    if (tid < N) {
        y1 = rois[tid * 4 + 0];
        x1 = rois[tid * 4 + 1];
        y2 = rois[tid * 4 + 2];
        x2 = rois[tid * 4 + 3];
        float h = y2 - y1;
        float w = x2 - x1;
        // lvl = round(log(sqrt(h*w))/log(2) - 5), clip [0,3]; rintf = RNE.
        float l = logf(sqrtf(h * w)) / logf(2.0f);
        int li = (int)rintf(l - 5.0f);
        lvl = li < 0 ? 0 : (li > 3 ? 3 : li);
    }

    unsigned long long mask[4];
    #pragma unroll
    for (int l = 0; l < 4; ++l) mask[l] = __ballot(lvl == l);
    if (lane == 0) {
        #pragma unroll
        for (int l = 0; l < 4; ++l) hist[wave][l] = __popcll(mask[l]);
    }
    __syncthreads();

    if (lvl >= 0) {
        int pos = __popcll(mask[lvl] & ((1ull << lane) - 1ull));
        for (int w2 = 0; w2 < wave; ++w2) pos += hist[w2][lvl];
        for (int l = 0; l < lvl; ++l)
            #pragma unroll
            for (int w2 = 0; w2 < 16; ++w2) pos += hist[w2][l];

        sorted_lvl[pos] = lvl;
        const float inv = 1.0f / 1024.0f;   // exact (power of two)
        sorted_box[pos] = make_float4(y1 * inv, x1 * inv, y2 * inv, x2 * inv);
    }
}

// ---------------------------------------------------------------------------
// Kernel 2: ONE BLOCK PER ROI. 448 threads = 7 waves; wave = pool row py,
// px loop unrolled inside the wave. All 49 positions of an ROI execute on a
// single CU, temporally adjacent:
//   - px -> px+1 shares 2 of 4 bilinear corner texels -> L1 hit
//   - row py's y1-row == row (py+1)'s y0-row          -> L1/L2 hit (same CU)
// Goal: dedup the 4x gather traffic (196 MB -> ~100 MB of unique window
// bytes) before it reaches L3/HBM, which round-0 counters suggest is the
// binding resource (~246 MB total at ~6-7 TB/s effective ~= 40 us).
// PLAIN stores this round: round-1's nontemporal stores are the suspected
// +7 us (50 MB forced direct-to-HBM); this isolates the structure variable.
// Lane l handles channels [4l,4l+4) as float4: 16B/lane coalesced.
// ---------------------------------------------------------------------------
__global__ void __launch_bounds__(448) roi_align_kernel(
    const float* __restrict__ f0, const float* __restrict__ f1,
    const float* __restrict__ f2, const float* __restrict__ f3,
    const int* __restrict__ sorted_lvl, const float4* __restrict__ sorted_box,
    float* __restrict__ out)
{
    const int n    = blockIdx.x;
    const int py   = threadIdx.x >> 6;   // 0..6  (wave index = pool row)
    const int lane = threadIdx.x & 63;   // channel group

    const int lvl = sorted_lvl[n];
    const float4 box = sorted_box[n];

    const float* feat;
    int HW;
    switch (lvl) {
        case 0:  feat = f0; HW = 256; break;
        case 1:  feat = f1; HW = 128; break;
        case 2:  feat = f2; HW = 64;  break;
        default: feat = f3; HW = 32;  break;
    }
    const float Hm1 = (float)(HW - 1);

    // iy = y1*(H-1) + py * (y2-y1)*(H-1)/6   (same for x, W=H)
    const float sy = (box.z - box.x) * Hm1 * (1.0f / 6.0f);
    const float sx = (box.w - box.y) * Hm1 * (1.0f / 6.0f);

    const float iy  = box.x * Hm1 + (float)py * sy;
    const float y0f = floorf(iy);
    const float ly  = iy - y0f;
    int y0  = (int)y0f;
    int y1i = y0 + 1;
    y0  = min(max(y0,  0), HW - 1);
    y1i = min(max(y1i, 0), HW - 1);
    const bool vy = (iy >= 0.0f) & (iy <= Hm1);

    // Per-wave row bases: all px iterations read from these two feature rows.
    const float4* row0 = (const float4*)(feat + (size_t)(y0  * HW) * CHANS) + lane;
    const float4* row1 = (const float4*)(feat + (size_t)(y1i * HW) * CHANS) + lane;

    float4* outp = (float4*)(out + (size_t)n * (POOL_H * POOL_W * CHANS))
                   + py * (POOL_W * 64) + lane;

    const float ix_base = box.y * Hm1;

    #pragma unroll
    for (int px = 0; px < POOL_W; ++px) {
        const float ix  = ix_base + (float)px * sx;
        const float x0f = floorf(ix);
        const float lx  = ix - x0f;
        int x0  = (int)x0f;
        int x1i = x0 + 1;
        x0  = min(max(x0,  0), HW - 1);
        x1i = min(max(x1i, 0), HW - 1);
        const bool valid = vy & (ix >= 0.0f) & (ix <= Hm1);

        const float4 f00 = row0[(size_t)x0  * 64];
        const float4 f01 = row0[(size_t)x1i * 64];
        const float4 f10 = row1[(size_t)x0  * 64];
        const float4 f11 = row1[(size_t)x1i * 64];

        float4 val;
        {
            float tx, bx;
            tx = f00.x + (f01.x - f00.x) * lx;
            bx = f10.x + (f11.x - f10.x) * lx;
            val.x = tx + (bx - tx) * ly;
            tx = f00.y + (f01.y - f00.y) * lx;
            bx = f10.y + (f11.y - f10.y) * lx;
            val.y = tx + (bx - tx) * ly;
            tx = f00.z + (f01.z - f00.z) * lx;
            bx = f10.z + (f11.z - f10.z) * lx;
            val.z = tx + (bx - tx) * ly;
            tx = f00.w + (f01.w - f00.w) * lx;
            bx = f10.w + (f11.w - f10.w) * lx;
            val.w = tx + (bx - tx) * ly;
        }
        if (!valid) { val.x = 0.f; val.y = 0.f; val.z = 0.f; val.w = 0.f; }

        outp[px * 64] = val;
    }
}

extern "C" void kernel_launch(void* const* d_in, const int* in_sizes, int n_in,
                              void* d_out, int out_size, void* d_ws, size_t ws_size,
                              hipStream_t stream) {
    const float* f0   = (const float*)d_in[0];
    const float* f1   = (const float*)d_in[1];
    const float* f2   = (const float*)d_in[2];
    const float* f3   = (const float*)d_in[3];
    const float* rois = (const float*)d_in[4];
    const int N = in_sizes[4] / 4;

    int*    sorted_lvl = (int*)d_ws;
    float4* sorted_box = (float4*)((char*)d_ws + 4096);
    float*  out        = (float*)d_out;

    hipLaunchKernelGGL(level_sort_kernel, dim3(1), dim3(1024), 0, stream,
                       rois, N, sorted_lvl, sorted_box);

    hipLaunchKernelGGL(roi_align_kernel, dim3(N), dim3(448), 0, stream,
                       f0, f1, f2, f3, sorted_lvl, sorted_box, out);
}

// Round 5
// 134.511 us; speedup vs baseline: 1.0773x; 1.0030x over previous
//
#include <hip/hip_runtime.h>

#define POOL_H 7
#define POOL_W 7
#define CHANS  256

// ---------------------------------------------------------------------------
// Kernel 1: per-ROI pyramid level + STABLE counting sort by level (matches
// jnp.argsort(lvl, stable=True)). Single block, 1024 threads (N=1000).
// Precise logf path kept: v_log_f32 risks flipping a ROI at a level boundary.
// ---------------------------------------------------------------------------
__global__ void __launch_bounds__(1024) level_sort_kernel(
    const float* __restrict__ rois, int N,
    int* __restrict__ sorted_lvl, float4* __restrict__ sorted_box)
{
    __shared__ int hist[16][4];   // [wave][level]

    const int tid  = threadIdx.x;
    const int wave = tid >> 6;
    const int lane = tid & 63;

    int lvl = -1;
    float y1 = 0.f, x1 = 0.f, y2 = 0.f, x2 = 0.f;
    if (tid < N) {
        y1 = rois[tid * 4 + 0];
        x1 = rois[tid * 4 + 1];
        y2 = rois[tid * 4 + 2];
        x2 = rois[tid * 4 + 3];
        float h = y2 - y1;
        float w = x2 - x1;
        float l = logf(sqrtf(h * w)) / logf(2.0f);
        int li = (int)rintf(l - 5.0f);
        lvl = li < 0 ? 0 : (li > 3 ? 3 : li);
    }

    unsigned long long mask[4];
    #pragma unroll
    for (int l = 0; l < 4; ++l) mask[l] = __ballot(lvl == l);
    if (lane == 0) {
        #pragma unroll
        for (int l = 0; l < 4; ++l) hist[wave][l] = __popcll(mask[l]);
    }
    __syncthreads();

    if (lvl >= 0) {
        int pos = __popcll(mask[lvl] & ((1ull << lane) - 1ull));
        for (int w2 = 0; w2 < wave; ++w2) pos += hist[w2][lvl];
        for (int l = 0; l < lvl; ++l)
            #pragma unroll
            for (int w2 = 0; w2 < 16; ++w2) pos += hist[w2][l];

        sorted_lvl[pos] = lvl;
        const float inv = 1.0f / 1024.0f;   // exact (power of two)
        sorted_box[pos] = make_float4(y1 * inv, x1 * inv, y2 * inv, x2 * inv);
    }
}

// ---------------------------------------------------------------------------
// Kernel 2: ONE BLOCK PER ROI, wave = pool row py, px swept in-wave.
// NEW: register-carried texel dedup. All x indices are wave-uniform and
// monotone in px, so the two texel columns loaded at step px are cached in
// registers and reused at px+1 when x lands on a cached column. This dedups
// BEFORE L1 (r4 showed L1 can't do it: 28 waves x 4KB in-flight rows thrash
// 32KB L1). Expected ~30-40% fewer gather loads -> less L1/fabric traffic,
// which r0/r4 equality suggests is the binding resource (~246 MB @ ~6.4TB/s).
// Branches are wave-uniform (x from box, not from load data): no divergence,
// no new memory-serial dependence.
// ---------------------------------------------------------------------------
__global__ void __launch_bounds__(448) roi_align_kernel(
    const float* __restrict__ f0, const float* __restrict__ f1,
    const float* __restrict__ f2, const float* __restrict__ f3,
    const int* __restrict__ sorted_lvl, const float4* __restrict__ sorted_box,
    float* __restrict__ out)
{
    const int n    = blockIdx.x;
    const int py   = threadIdx.x >> 6;   // 0..6  (wave index = pool row)
    const int lane = threadIdx.x & 63;   // channel group

    const int lvl = sorted_lvl[n];
    const float4 box = sorted_box[n];

    const float* feat;
    int HW;
    switch (lvl) {
        case 0:  feat = f0; HW = 256; break;
        case 1:  feat = f1; HW = 128; break;
        case 2:  feat = f2; HW = 64;  break;
        default: feat = f3; HW = 32;  break;
    }
    const float Hm1 = (float)(HW - 1);

    const float sy = (box.z - box.x) * Hm1 * (1.0f / 6.0f);
    const float sx = (box.w - box.y) * Hm1 * (1.0f / 6.0f);

    const float iy  = box.x * Hm1 + (float)py * sy;
    const float y0f = floorf(iy);
    const float ly  = iy - y0f;
    int y0  = (int)y0f;
    int y1i = y0 + 1;
    y0  = min(max(y0,  0), HW - 1);
    y1i = min(max(y1i, 0), HW - 1);
    const bool vy = (iy >= 0.0f) & (iy <= Hm1);

    const float4* row0 = (const float4*)(feat + (size_t)(y0  * HW) * CHANS) + lane;
    const float4* row1 = (const float4*)(feat + (size_t)(y1i * HW) * CHANS) + lane;

    float4* outp = (float4*)(out + (size_t)n * (POOL_H * POOL_W * CHANS))
                   + py * (POOL_W * 64) + lane;

    const float ix_base = box.y * Hm1;

    // Register texel cache: columns cx0 < cx1 (wave-uniform), texels for
    // row0/row1 at those columns. x0/x1i are monotone nondecreasing in px.
    int cx0 = -9, cx1 = -9;
    float4 r00c, r01c, r10c, r11c;

    #pragma unroll
    for (int px = 0; px < POOL_W; ++px) {
        const float ix  = ix_base + (float)px * sx;
        const float x0f = floorf(ix);
        const float lx  = ix - x0f;
        int x0  = (int)x0f;
        int x1i = x0 + 1;
        x0  = min(max(x0,  0), HW - 1);
        x1i = min(max(x1i, 0), HW - 1);
        const bool valid = vy & (ix >= 0.0f) & (ix <= Hm1);

        float4 f00, f01, f10, f11;
        if (x0 == cx1)      { f00 = r01c; f10 = r11c; }
        else if (x0 == cx0) { f00 = r00c; f10 = r10c; }
        else                { f00 = row0[(size_t)x0 * 64];
                              f10 = row1[(size_t)x0 * 64]; }

        if (x1i == x0)       { f01 = f00;  f11 = f10;  }   // right-edge clamp
        else if (x1i == cx1) { f01 = r01c; f11 = r11c; }
        else                 { f01 = row0[(size_t)x1i * 64];
                               f11 = row1[(size_t)x1i * 64]; }

        cx0 = x0; cx1 = x1i;
        r00c = f00; r01c = f01; r10c = f10; r11c = f11;

        float4 val;
        {
            float tx, bx;
            tx = f00.x + (f01.x - f00.x) * lx;
            bx = f10.x + (f11.x - f10.x) * lx;
            val.x = tx + (bx - tx) * ly;
            tx = f00.y + (f01.y - f00.y) * lx;
            bx = f10.y + (f11.y - f10.y) * lx;
            val.y = tx + (bx - tx) * ly;
            tx = f00.z + (f01.z - f00.z) * lx;
            bx = f10.z + (f11.z - f10.z) * lx;
            val.z = tx + (bx - tx) * ly;
            tx = f00.w + (f01.w - f00.w) * lx;
            bx = f10.w + (f11.w - f10.w) * lx;
            val.w = tx + (bx - tx) * ly;
        }
        if (!valid) { val.x = 0.f; val.y = 0.f; val.z = 0.f; val.w = 0.f; }

        outp[px * 64] = val;
    }
}

extern "C" void kernel_launch(void* const* d_in, const int* in_sizes, int n_in,
                              void* d_out, int out_size, void* d_ws, size_t ws_size,
                              hipStream_t stream) {
    const float* f0   = (const float*)d_in[0];
    const float* f1   = (const float*)d_in[1];
    const float* f2   = (const float*)d_in[2];
    const float* f3   = (const float*)d_in[3];
    const float* rois = (const float*)d_in[4];
    const int N = in_sizes[4] / 4;

    int*    sorted_lvl = (int*)d_ws;
    float4* sorted_box = (float4*)((char*)d_ws + 4096);
    float*  out        = (float*)d_out;

    hipLaunchKernelGGL(level_sort_kernel, dim3(1), dim3(1024), 0, stream,
                       rois, N, sorted_lvl, sorted_box);

    hipLaunchKernelGGL(roi_align_kernel, dim3(N), dim3(448), 0, stream,
                       f0, f1, f2, f3, sorted_lvl, sorted_box, out);
}

// Round 6
// 134.323 us; speedup vs baseline: 1.0788x; 1.0014x over previous
//
#include <hip/hip_runtime.h>

#define POOL_H 7
#define POOL_W 7
#define CHANS  256

// ---------------------------------------------------------------------------
// Kernel 1: per-ROI pyramid level + STABLE counting sort by level (output
// order, matches jnp.argsort(lvl, stable=True)), PLUS a spatial-major
// counting sort defining kernel 2's EXECUTION order.
//   exec key = (64px-region(y1,x1) << 2) | lvl   -- spatial major, level minor
// so temporally/concurrently executing blocks read NEIGHBORING feature rows:
// DRAM row-buffer hits + L2/L3 sharing of overlapping ROI windows. Levels
// stay interleaved across the grid (no per-XCD imbalance -- r3's bug). The
// 1024-bin prefix sum is a parallel Hillis-Steele scan (~1 us), not r3's
// serial loop.
// ---------------------------------------------------------------------------
__global__ void __launch_bounds__(1024) level_sort_kernel(
    const float* __restrict__ rois, int N,
    int* __restrict__ sorted_lvl, float4* __restrict__ sorted_box,
    int* __restrict__ exec_slot)
{
    __shared__ int hist[16][4];   // [wave][level] for the stable output sort
    __shared__ int bin[1024];     // spatial-bucket counts
    __shared__ int scan[1024];    // inclusive prefix
    __shared__ int bincnt[1024];  // arrival counters

    const int tid  = threadIdx.x;
    const int wave = tid >> 6;
    const int lane = tid & 63;

    int lvl = -1, key = 0;
    float y1 = 0.f, x1 = 0.f, y2 = 0.f, x2 = 0.f;
    if (tid < N) {
        y1 = rois[tid * 4 + 0];
        x1 = rois[tid * 4 + 1];
        y2 = rois[tid * 4 + 2];
        x2 = rois[tid * 4 + 3];
        float h = y2 - y1;
        float w = x2 - x1;
        // lvl = round(log(sqrt(h*w))/log(2) - 5), clip [0,3]; rintf = RNE.
        // Precise logf kept: v_log_f32 could flip a ROI at a level boundary.
        float l = logf(sqrtf(h * w)) / logf(2.0f);
        int li = (int)rintf(l - 5.0f);
        lvl = li < 0 ? 0 : (li > 3 ? 3 : li);
        int yb = (int)(y1 * (1.0f / 64.0f)); yb = yb < 0 ? 0 : (yb > 15 ? 15 : yb);
        int xb = (int)(x1 * (1.0f / 64.0f)); xb = xb < 0 ? 0 : (xb > 15 ? 15 : xb);
        key = (((yb << 4) | xb) << 2) | lvl;
    }

    unsigned long long mask[4];
    #pragma unroll
    for (int l = 0; l < 4; ++l) mask[l] = __ballot(lvl == l);
    if (lane == 0) {
        #pragma unroll
        for (int l = 0; l < 4; ++l) hist[wave][l] = __popcll(mask[l]);
    }
    bin[tid] = 0; bincnt[tid] = 0;
    __syncthreads();

    if (lvl >= 0) atomicAdd(&bin[key], 1);
    __syncthreads();

    // Hillis-Steele inclusive scan over 1024 bins (10 steps).
    scan[tid] = bin[tid];
    __syncthreads();
    #pragma unroll
    for (int off = 1; off < 1024; off <<= 1) {
        int v = scan[tid];
        if (tid >= off) v += scan[tid - off];
        __syncthreads();
        scan[tid] = v;
        __syncthreads();
    }

    if (lvl >= 0) {
        // stable (lvl, idx) output position
        int pos = __popcll(mask[lvl] & ((1ull << lane) - 1ull));
        for (int w2 = 0; w2 < wave; ++w2) pos += hist[w2][lvl];
        for (int l = 0; l < lvl; ++l)
            #pragma unroll
            for (int w2 = 0; w2 < 16; ++w2) pos += hist[w2][l];

        sorted_lvl[pos] = lvl;
        const float inv = 1.0f / 1024.0f;   // exact (power of two)
        sorted_box[pos] = make_float4(y1 * inv, x1 * inv, y2 * inv, x2 * inv);

        // spatial-major execution position (within-bin order arbitrary)
        int e = (scan[key] - bin[key]) + atomicAdd(&bincnt[key], 1);
        exec_slot[e] = pos;   // execution position e -> output slot pos
    }
}

// ---------------------------------------------------------------------------
// Kernel 2: r0 champion structure. grid (N, 13) x 256 threads; each of the 4
// waves in a block owns ONE (py,px) position: p = blockIdx.y*4 + wave. All
// four bilinear-corner loads issue immediately -> 49000 independent waves.
// Lane l handles channels [4l,4l+4) as float4: 16B/lane coalesced.
// ONLY change vs r0: block b processes exec_slot[b] (spatially-ordered),
// so concurrent blocks gather from neighboring feature rows.
// ---------------------------------------------------------------------------
__global__ void __launch_bounds__(256) roi_align_kernel(
    const float* __restrict__ f0, const float* __restrict__ f1,
    const float* __restrict__ f2, const float* __restrict__ f3,
    const int* __restrict__ sorted_lvl, const float4* __restrict__ sorted_box,
    const int* __restrict__ exec_slot,
    float* __restrict__ out)
{
    const int wave = threadIdx.x >> 6;
    const int lane = threadIdx.x & 63;

    const int p = blockIdx.y * 4 + wave;
    if (p >= POOL_H * POOL_W) return;

    const int slot = exec_slot[blockIdx.x];
    const int lvl = sorted_lvl[slot];
    const float4 box = sorted_box[slot];

    const float* feat;
    int HW;
    switch (lvl) {
        case 0:  feat = f0; HW = 256; break;
        case 1:  feat = f1; HW = 128; break;
        case 2:  feat = f2; HW = 64;  break;
        default: feat = f3; HW = 32;  break;
    }
    const float Hm1 = (float)(HW - 1);

    const int py = p / POOL_W;
    const int px = p % POOL_W;

    const float iy = box.x * Hm1 + (float)py * ((box.z - box.x) * Hm1 * (1.0f / 6.0f));
    const float ix = box.y * Hm1 + (float)px * ((box.w - box.y) * Hm1 * (1.0f / 6.0f));

    const float y0f = floorf(iy);
    const float x0f = floorf(ix);
    const float ly = iy - y0f;
    const float lx = ix - x0f;

    int y0  = (int)y0f;
    int x0  = (int)x0f;
    int y1i = y0 + 1;
    int x1i = x0 + 1;
    y0  = min(max(y0, 0), HW - 1);
    y1i = min(max(y1i, 0), HW - 1);
    x0  = min(max(x0, 0), HW - 1);
    x1i = min(max(x1i, 0), HW - 1);

    const bool valid = (iy >= 0.0f) & (iy <= Hm1) & (ix >= 0.0f) & (ix <= Hm1);

    const float4* p00 = (const float4*)(feat + ((size_t)(y0  * HW + x0 )) * CHANS) + lane;
    const float4* p01 = (const float4*)(feat + ((size_t)(y0  * HW + x1i)) * CHANS) + lane;
    const float4* p10 = (const float4*)(feat + ((size_t)(y1i * HW + x0 )) * CHANS) + lane;
    const float4* p11 = (const float4*)(feat + ((size_t)(y1i * HW + x1i)) * CHANS) + lane;

    const float4 f00 = *p00;
    const float4 f01 = *p01;
    const float4 f10 = *p10;
    const float4 f11 = *p11;

    float4 val;
    {
        float tx, bx;
        tx = f00.x + (f01.x - f00.x) * lx;
        bx = f10.x + (f11.x - f10.x) * lx;
        val.x = tx + (bx - tx) * ly;
        tx = f00.y + (f01.y - f00.y) * lx;
        bx = f10.y + (f11.y - f10.y) * lx;
        val.y = tx + (bx - tx) * ly;
        tx = f00.z + (f01.z - f00.z) * lx;
        bx = f10.z + (f11.z - f10.z) * lx;
        val.z = tx + (bx - tx) * ly;
        tx = f00.w + (f01.w - f00.w) * lx;
        bx = f10.w + (f11.w - f10.w) * lx;
        val.w = tx + (bx - tx) * ly;
    }
    if (!valid) { val.x = 0.f; val.y = 0.f; val.z = 0.f; val.w = 0.f; }

    float4* outn = (float4*)(out + (size_t)slot * (POOL_H * POOL_W * CHANS));
    outn[p * 64 + lane] = val;
}

extern "C" void kernel_launch(void* const* d_in, const int* in_sizes, int n_in,
                              void* d_out, int out_size, void* d_ws, size_t ws_size,
                              hipStream_t stream) {
    const float* f0   = (const float*)d_in[0];
    const float* f1   = (const float*)d_in[1];
    const float* f2   = (const float*)d_in[2];
    const float* f3   = (const float*)d_in[3];
    const float* rois = (const float*)d_in[4];
    const int N = in_sizes[4] / 4;

    int*    sorted_lvl = (int*)d_ws;
    float4* sorted_box = (float4*)((char*)d_ws + 4096);
    int*    exec_slot  = (int*)((char*)d_ws + 24576);
    float*  out        = (float*)d_out;

    hipLaunchKernelGGL(level_sort_kernel, dim3(1), dim3(1024), 0, stream,
                       rois, N, sorted_lvl, sorted_box, exec_slot);

    const int npos_blocks = (POOL_H * POOL_W + 3) / 4;   // 13
    hipLaunchKernelGGL(roi_align_kernel, dim3(N, npos_blocks), dim3(256), 0, stream,
                       f0, f1, f2, f3, sorted_lvl, sorted_box, exec_slot, out);
}

// Round 7
// 133.124 us; speedup vs baseline: 1.0885x; 1.0090x over previous
//
#include <hip/hip_runtime.h>

#define POOL_H 7
#define POOL_W 7
#define CHANS  256

// ---------------------------------------------------------------------------
// Kernel 1: per-ROI pyramid level + STABLE counting sort by level (matches
// jnp.argsort(lvl, stable=True)). Single block, 1024 threads (N=1000).
// LEAN version (champion r0): no spatial bins, no prefix scan — r3/r5/r6
// proved execution-reorder machinery costs 1-5 us for zero benefit.
// Precise logf path kept: v_log_f32 risks flipping a ROI at a level boundary.
// ---------------------------------------------------------------------------
__global__ void __launch_bounds__(1024) level_sort_kernel(
    const float* __restrict__ rois, int N,
    int* __restrict__ sorted_lvl, float4* __restrict__ sorted_box)
{
    __shared__ int hist[16][4];   // [wave][level]

    const int tid  = threadIdx.x;
    const int wave = tid >> 6;
    const int lane = tid & 63;

    int lvl = -1;
    float y1 = 0.f, x1 = 0.f, y2 = 0.f, x2 = 0.f;
    if (tid < N) {
        y1 = rois[tid * 4 + 0];
        x1 = rois[tid * 4 + 1];
        y2 = rois[tid * 4 + 2];
        x2 = rois[tid * 4 + 3];
        float h = y2 - y1;
        float w = x2 - x1;
        // lvl = round(log(sqrt(h*w))/log(2) - 5), clip [0,3]; rintf = RNE.
        float l = logf(sqrtf(h * w)) / logf(2.0f);
        int li = (int)rintf(l - 5.0f);
        lvl = li < 0 ? 0 : (li > 3 ? 3 : li);
    }

    unsigned long long mask[4];
    #pragma unroll
    for (int l = 0; l < 4; ++l) mask[l] = __ballot(lvl == l);
    if (lane == 0) {
        #pragma unroll
        for (int l = 0; l < 4; ++l) hist[wave][l] = __popcll(mask[l]);
    }
    __syncthreads();

    if (lvl >= 0) {
        int pos = __popcll(mask[lvl] & ((1ull << lane) - 1ull));
        for (int w2 = 0; w2 < wave; ++w2) pos += hist[w2][lvl];
        for (int l = 0; l < lvl; ++l)
            #pragma unroll
            for (int w2 = 0; w2 < 16; ++w2) pos += hist[w2][l];

        sorted_lvl[pos] = lvl;
        const float inv = 1.0f / 1024.0f;   // exact (power of two)
        sorted_box[pos] = make_float4(y1 * inv, x1 * inv, y2 * inv, x2 * inv);
    }
}

// ---------------------------------------------------------------------------
// Kernel 2 (champion r0): grid (N, 13) x 256 threads. Each of the 4 waves in
// a block owns EXACTLY ONE (py,px) position: p = blockIdx.y*4 + wave (p < 49).
// All four bilinear-corner loads issue immediately with no serial loop ->
// 49000 independent waves of memory-level parallelism. Lane l handles
// channels [4l,4l+4) as float4: 16B/lane coalesced loads and stores.
// A/B history: per-ROI-block (r4), register dedup (r5), and spatial exec
// ordering (r6) were all neutral; NT stores (r1) cost +3-5 us. k2 sits at
// its compulsory-traffic floor (~72 MB unique fetch post-poison + 50 MB
// stores); structure above that floor doesn't matter.
// ---------------------------------------------------------------------------
__global__ void __launch_bounds__(256) roi_align_kernel(
    const float* __restrict__ f0, const float* __restrict__ f1,
    const float* __restrict__ f2, const float* __restrict__ f3,
    const int* __restrict__ sorted_lvl, const float4* __restrict__ sorted_box,
    float* __restrict__ out)
{
    const int n    = blockIdx.x;
    const int wave = threadIdx.x >> 6;
    const int lane = threadIdx.x & 63;

    const int p = blockIdx.y * 4 + wave;
    if (p >= POOL_H * POOL_W) return;

    const int lvl = sorted_lvl[n];
    const float4 box = sorted_box[n];

    const float* feat;
    int HW;
    switch (lvl) {
        case 0:  feat = f0; HW = 256; break;
        case 1:  feat = f1; HW = 128; break;
        case 2:  feat = f2; HW = 64;  break;
        default: feat = f3; HW = 32;  break;
    }
    const float Hm1 = (float)(HW - 1);

    const int py = p / POOL_W;
    const int px = p % POOL_W;

    // iy = y1*(H-1) + py * (y2-y1)*(H-1)/6   (same for x, W=H)
    const float iy = box.x * Hm1 + (float)py * ((box.z - box.x) * Hm1 * (1.0f / 6.0f));
    const float ix = box.y * Hm1 + (float)px * ((box.w - box.y) * Hm1 * (1.0f / 6.0f));

    const float y0f = floorf(iy);
    const float x0f = floorf(ix);
    const float ly = iy - y0f;
    const float lx = ix - x0f;

    int y0  = (int)y0f;
    int x0  = (int)x0f;
    int y1i = y0 + 1;
    int x1i = x0 + 1;
    y0  = min(max(y0, 0), HW - 1);
    y1i = min(max(y1i, 0), HW - 1);
    x0  = min(max(x0, 0), HW - 1);
    x1i = min(max(x1i, 0), HW - 1);

    const bool valid = (iy >= 0.0f) & (iy <= Hm1) & (ix >= 0.0f) & (ix <= Hm1);

    const float4* p00 = (const float4*)(feat + ((size_t)(y0  * HW + x0 )) * CHANS) + lane;
    const float4* p01 = (const float4*)(feat + ((size_t)(y0  * HW + x1i)) * CHANS) + lane;
    const float4* p10 = (const float4*)(feat + ((size_t)(y1i * HW + x0 )) * CHANS) + lane;
    const float4* p11 = (const float4*)(feat + ((size_t)(y1i * HW + x1i)) * CHANS) + lane;

    const float4 f00 = *p00;
    const float4 f01 = *p01;
    const float4 f10 = *p10;
    const float4 f11 = *p11;

    float4 val;
    {
        float tx, bx;
        tx = f00.x + (f01.x - f00.x) * lx;
        bx = f10.x + (f11.x - f10.x) * lx;
        val.x = tx + (bx - tx) * ly;
        tx = f00.y + (f01.y - f00.y) * lx;
        bx = f10.y + (f11.y - f10.y) * lx;
        val.y = tx + (bx - tx) * ly;
        tx = f00.z + (f01.z - f00.z) * lx;
        bx = f10.z + (f11.z - f10.z) * lx;
        val.z = tx + (bx - tx) * ly;
        tx = f00.w + (f01.w - f00.w) * lx;
        bx = f10.w + (f11.w - f10.w) * lx;
        val.w = tx + (bx - tx) * ly;
    }
    if (!valid) { val.x = 0.f; val.y = 0.f; val.z = 0.f; val.w = 0.f; }

    float4* outn = (float4*)(out + (size_t)n * (POOL_H * POOL_W * CHANS));
    outn[p * 64 + lane] = val;
}

extern "C" void kernel_launch(void* const* d_in, const int* in_sizes, int n_in,
                              void* d_out, int out_size, void* d_ws, size_t ws_size,
                              hipStream_t stream) {
    const float* f0   = (const float*)d_in[0];
    const float* f1   = (const float*)d_in[1];
    const float* f2   = (const float*)d_in[2];
    const float* f3   = (const float*)d_in[3];
    const float* rois = (const float*)d_in[4];
    const int N = in_sizes[4] / 4;

    int*    sorted_lvl = (int*)d_ws;
    float4* sorted_box = (float4*)((char*)d_ws + 4096);
    float*  out        = (float*)d_out;

    hipLaunchKernelGGL(level_sort_kernel, dim3(1), dim3(1024), 0, stream,
                       rois, N, sorted_lvl, sorted_box);

    const int npos_blocks = (POOL_H * POOL_W + 3) / 4;   // 13
    hipLaunchKernelGGL(roi_align_kernel, dim3(N, npos_blocks), dim3(256), 0, stream,
                       f0, f1, f2, f3, sorted_lvl, sorted_box, out);
}